// Round 8
// baseline (3674.538 us; speedup 1.0000x reference)
//
#include <hip/hip_runtime.h>

#define EMB 32
#define HID 256
#define TT  2048

typedef _Float16 f16x8 __attribute__((ext_vector_type(8)));
typedef float    f32x4 __attribute__((ext_vector_type(4)));

// ---- d_ws layout (bytes) ----
// BFRAG: [member 4][wave 4][gate-tile 4][kslot 9][lane 64] f16x8 = 589,824
//        B[k][n] fragment for mfma_f32_16x16x32_f16: lane holds n=lane&15,
//        k = (lane>>4)*8 + e (+32*kstep). Global row = gate*256 + 64r+16w+(lane&15);
//        global k = kslot-permuted (member-dependent, own-slots-first).
// BIAS : [r 4][w 4][col 16][gate 4] float = 4,096
// ACK  : int[32]
// FAST : [group 8][member 4][slot 2][dw 256] = 65,536  (same-XCD L2 exchange)
#define BIAS_OFF 589824
#define ACK_OFF  593920
#define FAST_OFF 594048
// SLOW region = d_out, same [group][member][slot][256 dw] layout = 65,536 B.
// Tag protocol as R4-R7: each half carries tag ((k>>1)&1) in bit0; slot = k&1;
// prep inits slot0=tag0, slot1=tag1 (first uses never false-match). Freshness
// proven by tags, not by which cache served the load; 12 stale FAST polls ->
// sticky escalation to SLOW (agent/MALL). Correct under any XCD placement.

__device__ __forceinline__ float rcp_fast(float v) { return __builtin_amdgcn_rcpf(v); }
__device__ __forceinline__ float sigmoid_fast(float v) { return rcp_fast(1.0f + __expf(-v)); }
__device__ __forceinline__ float tanh_fast(float v) {
    v = fminf(fmaxf(v, -15.0f), 15.0f);
    float e = __expf(2.0f * v);
    return (e - 1.0f) * rcp_fast(e + 1.0f);
}
// LDS-only barrier: no vmcnt drain — publish stores / polls stay in flight.
__device__ __forceinline__ void barrier_lds() {
    asm volatile("s_waitcnt lgkmcnt(0)\n\ts_barrier" ::: "memory");
}
__device__ __forceinline__ unsigned load_slow(const unsigned* p) {
    return __hip_atomic_load(p, __ATOMIC_RELAXED, __HIP_MEMORY_SCOPE_AGENT);
}
// member-r kslot permutation: slot 0 = x (k-step 0); slots 1,2 = own-h k-steps
// (a=1+2r, a+1); slots 3..8 = the 6 peer k-steps in ascending order.
__device__ __forceinline__ int kslot(int s, int a) {
    return (s == 0) ? 0 : (s == 1) ? a : (s == 2) ? (a + 1)
         : ((s - 2) < a ? (s - 2) : s);
}

// ---- prep: B-fragments, bias, ack, SLOW+FAST tag init. 273 x 256. ----
__global__ void prep_kernel(const float* __restrict__ W_ih,
                            const float* __restrict__ W_hh,
                            const float* __restrict__ b_ih,
                            const float* __restrict__ b_hh,
                            char* __restrict__ ws,
                            unsigned* __restrict__ outw) {
    int bid = blockIdx.x, t = threadIdx.x;
    if (bid < 144) {                         // B fragments: 36,864 f16x8
        int gid = bid * 256 + t;
        int lane = gid & 63, rest = gid >> 6;
        int s = rest % 9; rest /= 9;
        int gt = rest & 3; rest >>= 2;
        int w = rest & 3, r = rest >> 2;
        int ksg = kslot(s, 1 + 2 * r);
        int row = gt * 256 + r * 64 + w * 16 + (lane & 15);
        f16x8 v;
#pragma unroll
        for (int e = 0; e < 8; ++e) {
            int k = ksg * 32 + (lane >> 4) * 8 + e;
            float f = (k < EMB) ? W_ih[row * EMB + k] : W_hh[row * HID + (k - EMB)];
            v[e] = (_Float16)f;
        }
        ((f16x8*)ws)[gid] = v;
    } else if (bid == 144) {                 // bias + ack
        for (int i = t; i < 1024; i += 256) {
            int gt = i & 3, col = (i >> 2) & 15, w = (i >> 6) & 3, r = i >> 8;
            int row = gt * 256 + r * 64 + w * 16 + col;
            ((float*)(ws + BIAS_OFF))[i] = b_ih[row] + b_hh[row];
        }
        if (t < 32) ((int*)(ws + ACK_OFF))[t] = 0;
    } else if (bid < 209) {                  // SLOW tags (d_out), 16,384 dw
        int g = (bid - 145) * 256 + t;
        outw[g] = ((g >> 8) & 1) ? 0x00010001u : 0u;
    } else {                                 // FAST tags (d_ws)
        int g = (bid - 209) * 256 + t;
        ((unsigned*)(ws + FAST_OFF))[g] = ((g >> 8) & 1) ? 0x00010001u : 0u;
    }
}

// ---- recurrent kernel: 32 blocks (group = bid&7, member r = bid>>3), 256 thr ----
// A-image (LDS, double-buffered): [chain 16][k 296 padded] fp16; chains 8..15
// stay zero (M=8 real chains). A-frag: lane holds A[m=lane&15][k=(lane>>4)*8+e].
// C/D: lane holds D[m=4*quad+reg][n=lane&15] -> chain=4*quad+reg, hidx-col=lane&15.
__global__ __launch_bounds__(256) void rnn_kernel(const int* __restrict__ x,
                                                  const int* __restrict__ lengths,
                                                  const float* __restrict__ emb,
                                                  char* __restrict__ ws,
                                                  float* __restrict__ out_) {
    __shared__ __align__(16) _Float16 Aimg[2][16 * 296];

    const int bid = blockIdx.x;
    const int grp = bid & 7, r = bid >> 3;
    const int tid = threadIdx.x;
    const int w = tid >> 6, L = tid & 63;
    const int col = L & 15, quad = L >> 4;
    const int ka = 1 + 2 * r;

    // register-resident B fragments: 4 gate-tiles x 9 kslots = 144 regs
    f16x8 B[4][9];
    {
        const f16x8* Bp = (const f16x8*)ws + (size_t)((r * 4 + w) * 4) * 9 * 64;
#pragma unroll
        for (int gt = 0; gt < 4; ++gt)
#pragma unroll
            for (int s = 0; s < 9; ++s) B[gt][s] = Bp[(gt * 9 + s) * 64 + L];
    }
    const f32x4 bias = *(const f32x4*)(ws + BIAS_OFF + (size_t)((r * 4 + w) * 16 + col) * 16);

    int Lmax = 1, Lc[4];
#pragma unroll
    for (int c = 0; c < 8; ++c) {
        int v = lengths[grp * 8 + c]; v = v < 1 ? 1 : (v > TT ? TT : v);
        Lmax = v > Lmax ? v : Lmax;
    }
#pragma unroll
    for (int cg = 0; cg < 4; ++cg) {
        int v = lengths[grp * 8 + ((4 * quad + cg) & 7)];
        Lc[cg] = v < 1 ? 1 : (v > TT ? TT : v);
    }

    unsigned* slowG = (unsigned*)out_ + grp * 2048;
    unsigned* fastG = (unsigned*)(ws + FAST_OFF) + grp * 2048;
    unsigned* smine = slowG + r * 512;
    unsigned* fmine = fastG + r * 512;
    const int p0 = (r + 1) & 3, p1 = (r + 2) & 3, p2 = (r + 3) & 3;

    // init A-images: zero (rows 8..15 stay zero forever), then x(0)
    for (int i = tid; i < 2 * 16 * 296; i += 256) ((_Float16*)Aimg)[i] = (_Float16)0.0f;
    __syncthreads();
    const int c8 = tid >> 5, cl = tid & 31;
    {
        int tok = x[(grp * 8 + c8) * TT];
        Aimg[0][c8 * 296 + cl] = (_Float16)emb[tok * EMB + cl];
    }
    __syncthreads();

    const f32x4 zf = {0.f, 0.f, 0.f, 0.f};
    f32x4 acc[4];
#pragma unroll
    for (int gt = 0; gt < 4; ++gt) acc[gt] = zf;
    // prologue: own/x kslots (0..2) for step 0
#pragma unroll
    for (int s = 0; s < 3; ++s) {
        f16x8 af = *(const f16x8*)(Aimg[0] + col * 296 + quad * 8 + kslot(s, ka) * 32);
#pragma unroll
        for (int gt = 0; gt < 4; ++gt)
            acc[gt] = __builtin_amdgcn_mfma_f32_16x16x32_f16(af, B[gt][s], acc[gt], 0, 0, 0);
    }

    float cst[4] = {0, 0, 0, 0}, hst[4] = {0, 0, 0, 0};
    int mode = 0;   // 0 = FAST (same-XCD L2), 1 = SLOW (MALL), sticky

#pragma unroll 1
    for (int t = 0; t < Lmax; ++t) {
        const _Float16* __restrict__ Ac = Aimg[t & 1];
        _Float16* __restrict__ An = Aimg[(t + 1) & 1];

        // prefetch x(t+1) embedding (2 dependent global loads, consumed later)
        int tn = (t + 1 < TT) ? t + 1 : TT - 1;
        int tok = x[(grp * 8 + c8) * TT + tn];
        float ev = emb[tok * EMB + cl];

        // stage1: the 6 peer kslots complete the gates for step t
        {
            f16x8 af[6];
#pragma unroll
            for (int s = 0; s < 6; ++s)
                af[s] = *(const f16x8*)(Ac + col * 296 + quad * 8 + kslot(s + 3, ka) * 32);
#pragma unroll
            for (int s = 0; s < 6; ++s)
#pragma unroll
                for (int gt = 0; gt < 4; ++gt)
                    acc[gt] = __builtin_amdgcn_mfma_f32_16x16x32_f16(af[s], B[gt][s + 3], acc[gt], 0, 0, 0);
        }

        // activations + masked state update; lane: chains 4*quad+cg, hidx 64r+16w+col
        const unsigned tg = ((unsigned)(t + 1) >> 1) & 1u;
        const int slot = (t + 1) & 1;
        unsigned tv[4];
#pragma unroll
        for (int cg = 0; cg < 4; ++cg) {
            float iv = sigmoid_fast(acc[0][cg] + bias[0]);
            float fv = sigmoid_fast(acc[1][cg] + bias[1]);
            float gv = tanh_fast(acc[2][cg] + bias[2]);
            float ov = sigmoid_fast(acc[3][cg] + bias[3]);
            float cn = fv * cst[cg] + iv * gv;
            float hn = ov * tanh_fast(cn);
            bool keep = t < Lc[cg];
            cst[cg] = keep ? cn : cst[cg];
            hst[cg] = keep ? hn : hst[cg];
            unsigned short hb = __builtin_bit_cast(unsigned short, (_Float16)hst[cg]);
            tv[cg] = (unsigned)((hb & 0xFFFEu) | tg);
        }

        // dual-publish h(t+1): pair even/odd cols via DPP, FAST plain + SLOW agent
        unsigned nb[4];
#pragma unroll
        for (int cg = 0; cg < 4; ++cg)
            nb[cg] = (unsigned)__builtin_amdgcn_mov_dpp((int)tv[cg], 0xB1, 0xF, 0xF, true);
        if (quad < 2 && !(L & 1)) {
#pragma unroll
            for (int cg = 0; cg < 4; ++cg) {
                unsigned dw = tv[cg] | (nb[cg] << 16);
                int d = slot * 256 + (4 * quad + cg) * 32 + 8 * w + (col >> 1);
                __hip_atomic_store(fmine + d, dw, __ATOMIC_RELAXED, __HIP_MEMORY_SCOPE_WORKGROUP);
                __hip_atomic_store(smine + d, dw, __ATOMIC_RELAXED, __HIP_MEMORY_SCOPE_AGENT);
            }
        }
        // own h + x(t+1) into next A-image
        if (quad < 2) {
#pragma unroll
            for (int cg = 0; cg < 4; ++cg)
                An[(4 * quad + cg) * 296 + 32 + 64 * r + 16 * w + col] = (_Float16)hst[cg];
        }
        An[c8 * 296 + cl] = (_Float16)ev;
        barrier_lds();   // A

        // first polls, then own/x kslots for t+1 in the exchange shadow
        const unsigned* q0 = fastG + p0 * 512 + slot * 256 + tid;
        const unsigned* q1 = fastG + p1 * 512 + slot * 256 + tid;
        const unsigned* q2 = fastG + p2 * 512 + slot * 256 + tid;
        const unsigned* s0 = slowG + p0 * 512 + slot * 256 + tid;
        const unsigned* s1 = slowG + p1 * 512 + slot * 256 + tid;
        const unsigned* s2 = slowG + p2 * 512 + slot * 256 + tid;
        unsigned da, db, dc;
        if (mode) { da = load_slow(s0); db = load_slow(s1); dc = load_slow(s2); }
        else {
            da = *(volatile const unsigned*)q0;
            db = *(volatile const unsigned*)q1;
            dc = *(volatile const unsigned*)q2;
        }

#pragma unroll
        for (int gt = 0; gt < 4; ++gt) acc[gt] = zf;
#pragma unroll
        for (int s = 0; s < 3; ++s) {
            f16x8 af = *(const f16x8*)(An + col * 296 + quad * 8 + kslot(s, ka) * 32);
#pragma unroll
            for (int gt = 0; gt < 4; ++gt)
                acc[gt] = __builtin_amdgcn_mfma_f32_16x16x32_f16(af, B[gt][s], acc[gt], 0, 0, 0);
        }

        // finish the spin (sticky FAST->SLOW), land 3 peer dwords into An
        {
            int tries = 0;
            while (true) {
                bool ok = ((da & 1u) == tg) && (((da >> 16) & 1u) == tg)
                       && ((db & 1u) == tg) && (((db >> 16) & 1u) == tg)
                       && ((dc & 1u) == tg) && (((dc >> 16) & 1u) == tg);
                if (__all(ok)) break;
                if (++tries > (1 << 20)) break;
                if (mode == 0 && tries > 12) mode = 1;
                if (mode) {
                    __builtin_amdgcn_s_sleep(1);
                    da = load_slow(s0); db = load_slow(s1); dc = load_slow(s2);
                } else {
                    da = *(volatile const unsigned*)q0;
                    db = *(volatile const unsigned*)q1;
                    dc = *(volatile const unsigned*)q2;
                }
            }
        }
        {
            int kb = 32 + 2 * (tid & 31);
            int c = tid >> 5;
            *(unsigned*)(&An[c * 296 + kb + 64 * p0]) = da;
            *(unsigned*)(&An[c * 296 + kb + 64 * p1]) = db;
            *(unsigned*)(&An[c * 296 + kb + 64 * p2]) = dc;
        }
        barrier_lds();   // B
    }

    // drain all waves' stores, group-wide ack, then overwrite d_out with output
    __syncthreads();
    int* ack = (int*)(ws + ACK_OFF);
    if (tid == 0)
        __hip_atomic_store(&ack[bid], Lmax, __ATOMIC_RELEASE, __HIP_MEMORY_SCOPE_AGENT);
    if (tid < 3) {
        int pb = grp + 8 * ((r + 1 + tid) & 3);
        int tries = 0;
        while (__hip_atomic_load(&ack[pb], __ATOMIC_ACQUIRE, __HIP_MEMORY_SCOPE_AGENT) != Lmax) {
            if (++tries > (1 << 20)) break;
            __builtin_amdgcn_s_sleep(8);
        }
    }
    __syncthreads();
    if (quad < 2) {
#pragma unroll
        for (int cg = 0; cg < 4; ++cg)
            out_[(size_t)(grp * 8 + 4 * quad + cg) * 256 + 64 * r + 16 * w + col] = hst[cg];
    }
}

extern "C" void kernel_launch(void* const* d_in, const int* in_sizes, int n_in,
                              void* d_out, int out_size, void* d_ws, size_t ws_size,
                              hipStream_t stream) {
    const int*   x       = (const int*)d_in[0];
    const int*   lengths = (const int*)d_in[1];
    const float* emb     = (const float*)d_in[2];
    const float* W_ih    = (const float*)d_in[3];
    const float* W_hh    = (const float*)d_in[4];
    const float* b_ih    = (const float*)d_in[5];
    const float* b_hh    = (const float*)d_in[6];

    prep_kernel<<<273, 256, 0, stream>>>(W_ih, W_hh, b_ih, b_hh,
                                         (char*)d_ws, (unsigned*)d_out);
    rnn_kernel<<<32, 256, 0, stream>>>(x, lengths, emb, (char*)d_ws, (float*)d_out);
}